// Round 9
// baseline (7336.746 us; speedup 1.0000x reference)
//
#include <hip/hip_runtime.h>
#include <cstdint>
#include <cstddef>

#define NFILT 40
#define NBINS 257
#define HID   64
#define BB    64      // batch
#define TT    2000    // time
#define GATES 256     // 4*HID
#define MTOT  (BB*TT) // 128000 rows

// ---------- activations ----------
__device__ __forceinline__ float sigm(float x) {
  return 1.0f / (1.0f + __expf(-x));
}
__device__ __forceinline__ float tanh_(float x) {
  float e = __expf(-2.0f * fabsf(x));
  float r = (1.0f - e) / (1.0f + e);
  return copysignf(r, x);
}

// gate permutation: pre/W columns stored as g' = j*4 + q  (orig g = q*64 + j)
__device__ __forceinline__ int gperm(int gp) { return ((gp & 3) << 6) | (gp >> 2); }

// ---------- kernel 1: build fbank (40x257) + per-filter support bounds ----------
__global__ void k_fbank(const float* __restrict__ binpoints,
                        float* __restrict__ fbank,
                        int* __restrict__ lohi /*[2*NFILT]*/) {
  __shared__ float b[NFILT + 2];
  int tid = threadIdx.x;
  if (tid < NFILT + 2) b[tid] = binpoints[tid];
  __syncthreads();
  if (tid < NFILT) {
    if (tid == NFILT - 1) { lohi[tid] = 0; lohi[NFILT + tid] = 0; }
    else {
      int lo = (int)floorf(b[tid]);
      int hi = (int)floorf(b[tid + 2]);
      if (lo < 0) lo = 0;
      if (hi > NBINS) hi = NBINS;
      lohi[tid] = lo; lohi[NFILT + tid] = hi;
    }
  }
  for (int idx = tid; idx < NFILT * NBINS; idx += blockDim.x) {
    int f = idx / NBINS, i = idx - f * NBINS;
    float bj = b[f], bj1 = b[f + 1], bj2 = b[f + 2];
    float fb0 = floorf(bj), fb1 = floorf(bj1), fb2 = floorf(bj2);
    float fi = (float)i;
    bool rise = (fi >= fb0) && (fi < fb1);
    bool fall = (fi >= fb1) && (fi < fb2);
    float d1 = bj1 - bj;  d1 = (d1 > 0.f) ? d1 : 1.f;
    float d2 = bj2 - bj1; d2 = (d2 > 0.f) ? d2 : 1.f;
    float rv = (fi - bj)  / (d1 * d1);
    float fv = (bj2 - fi) / (d2 * d2);
    float v = fall ? fv : (rise ? rv : 0.f);
    if (f == NFILT - 1) v = 0.f;
    fbank[idx] = v;
  }
}

// ---------- kernel 2: featurize  h0[bt][f] = log(filt + 1e-10) ----------
__global__ __launch_bounds__(64) void k_feat(const float* __restrict__ x,
                                             const float* __restrict__ fbank,
                                             const int* __restrict__ lohi,
                                             float* __restrict__ h0) {
  int bt = blockIdx.x;
  __shared__ float xs[NBINS];
  const float* xr = x + (size_t)bt * NBINS;
  for (int i = threadIdx.x; i < NBINS; i += 64) xs[i] = xr[i];
  __syncthreads();
  int f = threadIdx.x;
  if (f < NFILT) {
    float acc = 0.f;
    int lo = lohi[f], hi = lohi[NFILT + f];
    for (int i = lo; i < hi; ++i) acc = fmaf(xs[i], fbank[f * NBINS + i], acc);
    float val = (f == 0) ? xs[0] : acc;
    h0[(size_t)bt * NFILT + f] = logf(val + 1e-10f);
  }
}

// ---------- kernel 3: fp32 GEMM, writes pre in permuted layout g'=j*4+q ----------
// (verbatim round-2 version; verified absmax 0)
template <int K, int BK>
__global__ __launch_bounds__(256) void k_gemm(const float* __restrict__ Hm,   // [MTOT][K]
                                              const float* __restrict__ W,    // [2][256][K] (orig rows)
                                              const float* __restrict__ bih,  // [2][256]
                                              const float* __restrict__ bhh,  // [2][256]
                                              float* __restrict__ pre) {      // [2][MTOT][256] permuted
  constexpr int BM = 128, BN = 64;
  __shared__ float Hs[BK][BM + 4];
  __shared__ float Ws[BK][BN + 4];
  const int d  = blockIdx.z;
  const int m0 = blockIdx.x * BM;
  const int g0 = blockIdx.y * BN;   // in g'-space
  const int tid = threadIdx.x;
  const int tx = tid & 15, ty = tid >> 4;

  float acc[8][4];
#pragma unroll
  for (int r = 0; r < 8; ++r)
#pragma unroll
    for (int j = 0; j < 4; ++j) acc[r][j] = 0.f;

  for (int k0 = 0; k0 < K; k0 += BK) {
    constexpr int HL = BM * BK / 256;
#pragma unroll
    for (int i = 0; i < HL; ++i) {
      int flat = tid + i * 256;
      int r = flat / BK, kk = flat - r * BK;
      Hs[kk][r] = Hm[(size_t)(m0 + r) * K + k0 + kk];
    }
    constexpr int WL = BN * BK / 256;
#pragma unroll
    for (int i = 0; i < WL; ++i) {
      int flat = tid + i * 256;
      int r = flat / BK, kk = flat - r * BK;
      Ws[kk][r] = W[((size_t)d * GATES + gperm(g0 + r)) * K + k0 + kk];
    }
    __syncthreads();
#pragma unroll
    for (int kk = 0; kk < BK; ++kk) {
      const float4 wv  = *(const float4*)&Ws[kk][tx * 4];
      const float4 hv0 = *(const float4*)&Hs[kk][ty * 8];
      const float4 hv1 = *(const float4*)&Hs[kk][ty * 8 + 4];
      const float hr[8] = {hv0.x, hv0.y, hv0.z, hv0.w, hv1.x, hv1.y, hv1.z, hv1.w};
#pragma unroll
      for (int r = 0; r < 8; ++r) {
        acc[r][0] = fmaf(hr[r], wv.x, acc[r][0]);
        acc[r][1] = fmaf(hr[r], wv.y, acc[r][1]);
        acc[r][2] = fmaf(hr[r], wv.z, acc[r][2]);
        acc[r][3] = fmaf(hr[r], wv.w, acc[r][3]);
      }
    }
    __syncthreads();
  }

  const int gcol = g0 + tx * 4;   // g'-space columns
  float bsum[4];
#pragma unroll
  for (int i = 0; i < 4; ++i) {
    const int og = gperm(gcol + i);
    bsum[i] = bih[d * GATES + og] + bhh[d * GATES + og];
  }
#pragma unroll
  for (int r = 0; r < 8; ++r) {
    size_t m = (size_t)(m0 + ty * 8 + r);
    float4 o = {acc[r][0] + bsum[0], acc[r][1] + bsum[1], acc[r][2] + bsum[2], acc[r][3] + bsum[3]};
    *(float4*)&pre[((size_t)d * MTOT + m) * GATES + gcol] = o;
  }
}

// ---------- kernel 4: recurrent LSTM, ONE WAVE per (b,d) — no barriers, no exchange ----------
// Lane j owns hidden unit j and holds ALL FOUR gate rows of whh (256 floats) in
// VGPRs. amdgpu_waves_per_eu(1,1) gives the 512-VGPR budget (round-8 proved the
// attribute makes weight arrays register-resident; round-2's spill at the default
// budget is what killed this shape before). Per step: 16 broadcast ds_read_b128
// of h from LDS (conflict-free), 256 fmac in 8 independent chains, activations,
// one ds_write_b32 of own h. Zero barriers, zero readlanes, zero cross-wave
// traffic; single-wave LDS is in-order (wave_barrier pins compiler ordering).
// pre consumed as one float4/lane/step via the gate-permuted GEMM layout.
// 4-deep HBM prefetch; nothing ever drains vmcnt on the serial path.
__global__ __attribute__((amdgpu_waves_per_eu(1, 1)))
__launch_bounds__(64) void k_lstm1w(const float* __restrict__ pre, // [2][B*T][64][4] permuted
                                    const float* __restrict__ whh, // [2][256][64] orig
                                    float* __restrict__ hout,      // [B][T][128]
                                    float* __restrict__ out,       // [B][128]
                                    int final_layer) {
  const int b = blockIdx.x & (BB - 1);
  const int d = blockIdx.x >> 6;
  const int j = threadIdx.x;
  __shared__ __align__(16) float h_s[HID];

  // 256 weights/lane: w[q*64+k] = whh[d][q*64+j][k]
  float w[256];
#pragma unroll
  for (int q = 0; q < 4; ++q) {
    const float4* wr = (const float4*)(whh + ((size_t)d * GATES + q * HID + j) * HID);
#pragma unroll
    for (int kk = 0; kk < 16; ++kk) {
      const float4 t4 = wr[kk];
      w[q * 64 + 4 * kk + 0] = t4.x; w[q * 64 + 4 * kk + 1] = t4.y;
      w[q * 64 + 4 * kk + 2] = t4.z; w[q * 64 + 4 * kk + 3] = t4.w;
    }
  }
#pragma unroll
  for (int kk = 0; kk < 256; ++kk) {
    asm volatile("" : "+v"(w[kk]));   // keep VGPR-resident (budget: waves_per_eu(1,1))
  }

  h_s[j] = 0.f;
  float c = 0.f, sum = 0.f;
  __builtin_amdgcn_wave_barrier();

  const size_t base = ((size_t)d * MTOT + (size_t)b * TT);
  const int t0 = d ? (TT - 1) : 0;
  const int dt = d ? -1 : 1;
  const float4* prow = (const float4*)pre;  // 64 float4 per row
  const float4* pp = prow + (base + (size_t)t0) * 64 + j;
  const ptrdiff_t pstr = (ptrdiff_t)dt * 64;

  float4 pf0 = pp[0], pf1 = pp[pstr], pf2 = pp[pstr * 2], pf3 = pp[pstr * 3];

#define LSTM_STEP(TK, PF)                                                       \
  do {                                                                          \
    __builtin_amdgcn_wave_barrier();  /* reads stay after prior step's write */ \
    const float4* h4 = (const float4*)h_s;                                      \
    float z0a = (PF).x, z0b = 0.f, z1a = (PF).y, z1b = 0.f;                     \
    float z2a = (PF).z, z2b = 0.f, z3a = (PF).w, z3b = 0.f;                     \
    _Pragma("unroll")                                                           \
    for (int kk = 0; kk < 16; ++kk) {                                           \
      const float4 hv = h4[kk];  /* wave-uniform addr: broadcast read */        \
      z0a = fmaf(hv.x, w[0 + 4 * kk + 0], z0a);                                 \
      z0b = fmaf(hv.y, w[0 + 4 * kk + 1], z0b);                                 \
      z0a = fmaf(hv.z, w[0 + 4 * kk + 2], z0a);                                 \
      z0b = fmaf(hv.w, w[0 + 4 * kk + 3], z0b);                                 \
      z1a = fmaf(hv.x, w[64 + 4 * kk + 0], z1a);                                \
      z1b = fmaf(hv.y, w[64 + 4 * kk + 1], z1b);                                \
      z1a = fmaf(hv.z, w[64 + 4 * kk + 2], z1a);                                \
      z1b = fmaf(hv.w, w[64 + 4 * kk + 3], z1b);                                \
      z2a = fmaf(hv.x, w[128 + 4 * kk + 0], z2a);                               \
      z2b = fmaf(hv.y, w[128 + 4 * kk + 1], z2b);                               \
      z2a = fmaf(hv.z, w[128 + 4 * kk + 2], z2a);                               \
      z2b = fmaf(hv.w, w[128 + 4 * kk + 3], z2b);                               \
      z3a = fmaf(hv.x, w[192 + 4 * kk + 0], z3a);                               \
      z3b = fmaf(hv.y, w[192 + 4 * kk + 1], z3b);                               \
      z3a = fmaf(hv.z, w[192 + 4 * kk + 2], z3a);                               \
      z3b = fmaf(hv.w, w[192 + 4 * kk + 3], z3b);                               \
    }                                                                           \
    const float ig = sigm(z0a + z0b), fg = sigm(z1a + z1b);                     \
    const float gg = tanh_(z2a + z2b), og = sigm(z3a + z3b);                    \
    c = fmaf(fg, c, ig * gg);                                                   \
    const float hvv = og * tanh_(c);                                            \
    __builtin_amdgcn_wave_barrier();  /* write stays after this step's reads */ \
    h_s[j] = hvv;                                                               \
    if (final_layer) sum += hvv;                                                \
    else                                                                        \
      hout[((size_t)b * TT + (size_t)(t0 + dt * (TK))) * (2 * HID) + d * HID + j] = hvv; \
  } while (0)

  for (int t = 0; t < TT; t += 4) {
    LSTM_STEP(t + 0, pf0);
    { int ip = t + 4; if (ip >= TT) ip = 0; pf0 = pp[pstr * (ptrdiff_t)ip]; }
    LSTM_STEP(t + 1, pf1);
    { int ip = t + 5; if (ip >= TT) ip = 0; pf1 = pp[pstr * (ptrdiff_t)ip]; }
    LSTM_STEP(t + 2, pf2);
    { int ip = t + 6; if (ip >= TT) ip = 0; pf2 = pp[pstr * (ptrdiff_t)ip]; }
    LSTM_STEP(t + 3, pf3);
    { int ip = t + 7; if (ip >= TT) ip = 0; pf3 = pp[pstr * (ptrdiff_t)ip]; }
  }
#undef LSTM_STEP

  if (final_layer) out[b * (2 * HID) + d * HID + j] = sum * (1.0f / (float)TT);
}

// ---------- launch ----------
extern "C" void kernel_launch(void* const* d_in, const int* in_sizes, int n_in,
                              void* d_out, int out_size, void* d_ws, size_t ws_size,
                              hipStream_t stream) {
  const float* x         = (const float*)d_in[0];
  const float* binpoints = (const float*)d_in[1];
  const float* w_ih[3] = {(const float*)d_in[2], (const float*)d_in[6],  (const float*)d_in[10]};
  const float* w_hh[3] = {(const float*)d_in[3], (const float*)d_in[7],  (const float*)d_in[11]};
  const float* b_ih[3] = {(const float*)d_in[4], (const float*)d_in[8],  (const float*)d_in[12]};
  const float* b_hh[3] = {(const float*)d_in[5], (const float*)d_in[9],  (const float*)d_in[13]};
  float* out = (float*)d_out;

  // workspace layout (~349 MB):
  //   pre  : 2*MTOT*256 f32 = 262,144,000 B
  //   Hbuf : MTOT*128 f32   =  65,536,000 B
  //   h0   : MTOT*40 f32    =  20,480,000 B
  //   fbank: 40*257 f32, lohi: 80 i32
  float* pre   = (float*)d_ws;
  float* Hbuf  = pre  + (size_t)2 * MTOT * GATES;
  float* h0    = Hbuf + (size_t)MTOT * 128;
  float* fbank = h0   + (size_t)MTOT * NFILT;
  int*   lohi  = (int*)(fbank + NFILT * NBINS);

  k_fbank<<<1, 256, 0, stream>>>(binpoints, fbank, lohi);
  k_feat<<<MTOT, 64, 0, stream>>>(x, fbank, lohi, h0);

  // layer 0 (K=40)
  k_gemm<40, 40><<<dim3(MTOT / 128, GATES / 64, 2), 256, 0, stream>>>(h0, w_ih[0], b_ih[0], b_hh[0], pre);
  k_lstm1w<<<BB * 2, 64, 0, stream>>>(pre, w_hh[0], Hbuf, out, 0);

  // layer 1 (K=128)
  k_gemm<128, 32><<<dim3(MTOT / 128, GATES / 64, 2), 256, 0, stream>>>(Hbuf, w_ih[1], b_ih[1], b_hh[1], pre);
  k_lstm1w<<<BB * 2, 64, 0, stream>>>(pre, w_hh[1], Hbuf, out, 0);

  // layer 2 (K=128)
  k_gemm<128, 32><<<dim3(MTOT / 128, GATES / 64, 2), 256, 0, stream>>>(Hbuf, w_ih[2], b_ih[2], b_hh[2], pre);
  k_lstm1w<<<BB * 2, 64, 0, stream>>>(pre, w_hh[2], Hbuf, out, 1);
}

// Round 10
// 4043.250 us; speedup vs baseline: 1.8146x; 1.8146x over previous
//
#include <hip/hip_runtime.h>
#include <cstdint>
#include <cstddef>

#define NFILT 40
#define NBINS 257
#define HID   64
#define BB    64      // batch
#define TT    2000    // time
#define GATES 256     // 4*HID
#define MTOT  (BB*TT) // 128000 rows

// ---------- activations ----------
__device__ __forceinline__ float sigm(float x) {
  return 1.0f / (1.0f + __expf(-x));
}
__device__ __forceinline__ float tanh_(float x) {
  float e = __expf(-2.0f * fabsf(x));
  float r = (1.0f - e) / (1.0f + e);
  return copysignf(r, x);
}

// ---------- kernel 1: build fbank (40x257) + per-filter support bounds ----------
__global__ void k_fbank(const float* __restrict__ binpoints,
                        float* __restrict__ fbank,
                        int* __restrict__ lohi /*[2*NFILT]*/) {
  __shared__ float b[NFILT + 2];
  int tid = threadIdx.x;
  if (tid < NFILT + 2) b[tid] = binpoints[tid];
  __syncthreads();
  if (tid < NFILT) {
    if (tid == NFILT - 1) { lohi[tid] = 0; lohi[NFILT + tid] = 0; }
    else {
      int lo = (int)floorf(b[tid]);
      int hi = (int)floorf(b[tid + 2]);
      if (lo < 0) lo = 0;
      if (hi > NBINS) hi = NBINS;
      lohi[tid] = lo; lohi[NFILT + tid] = hi;
    }
  }
  for (int idx = tid; idx < NFILT * NBINS; idx += blockDim.x) {
    int f = idx / NBINS, i = idx - f * NBINS;
    float bj = b[f], bj1 = b[f + 1], bj2 = b[f + 2];
    float fb0 = floorf(bj), fb1 = floorf(bj1), fb2 = floorf(bj2);
    float fi = (float)i;
    bool rise = (fi >= fb0) && (fi < fb1);
    bool fall = (fi >= fb1) && (fi < fb2);
    float d1 = bj1 - bj;  d1 = (d1 > 0.f) ? d1 : 1.f;
    float d2 = bj2 - bj1; d2 = (d2 > 0.f) ? d2 : 1.f;
    float rv = (fi - bj)  / (d1 * d1);
    float fv = (bj2 - fi) / (d2 * d2);
    float v = fall ? fv : (rise ? rv : 0.f);
    if (f == NFILT - 1) v = 0.f;
    fbank[idx] = v;
  }
}

// ---------- kernel 2: featurize  h0[bt][f] = log(filt + 1e-10) ----------
__global__ __launch_bounds__(64) void k_feat(const float* __restrict__ x,
                                             const float* __restrict__ fbank,
                                             const int* __restrict__ lohi,
                                             float* __restrict__ h0) {
  int bt = blockIdx.x;
  __shared__ float xs[NBINS];
  const float* xr = x + (size_t)bt * NBINS;
  for (int i = threadIdx.x; i < NBINS; i += 64) xs[i] = xr[i];
  __syncthreads();
  int f = threadIdx.x;
  if (f < NFILT) {
    float acc = 0.f;
    int lo = lohi[f], hi = lohi[NFILT + f];
    for (int i = lo; i < hi; ++i) acc = fmaf(xs[i], fbank[f * NBINS + i], acc);
    float val = (f == 0) ? xs[0] : acc;
    h0[(size_t)bt * NFILT + f] = logf(val + 1e-10f);
  }
}

// ---------- kernel 3: fp32 GEMM  pre[d][m][g] = H[m][:]·W[d][g][:] + bih + bhh ----------
template <int K, int BK>
__global__ __launch_bounds__(256) void k_gemm(const float* __restrict__ Hm,   // [MTOT][K]
                                              const float* __restrict__ W,    // [2][256][K]
                                              const float* __restrict__ bih,  // [2][256]
                                              const float* __restrict__ bhh,  // [2][256]
                                              float* __restrict__ pre) {      // [2][MTOT][256]
  constexpr int BM = 128, BN = 64;
  __shared__ float Hs[BK][BM + 4];
  __shared__ float Ws[BK][BN + 4];
  const int d  = blockIdx.z;
  const int m0 = blockIdx.x * BM;
  const int g0 = blockIdx.y * BN;
  const int tid = threadIdx.x;
  const int tx = tid & 15, ty = tid >> 4;

  float acc[8][4];
#pragma unroll
  for (int r = 0; r < 8; ++r)
#pragma unroll
    for (int j = 0; j < 4; ++j) acc[r][j] = 0.f;

  for (int k0 = 0; k0 < K; k0 += BK) {
    constexpr int HL = BM * BK / 256;
#pragma unroll
    for (int i = 0; i < HL; ++i) {
      int flat = tid + i * 256;
      int r = flat / BK, kk = flat - r * BK;
      Hs[kk][r] = Hm[(size_t)(m0 + r) * K + k0 + kk];
    }
    constexpr int WL = BN * BK / 256;
#pragma unroll
    for (int i = 0; i < WL; ++i) {
      int flat = tid + i * 256;
      int r = flat / BK, kk = flat - r * BK;
      Ws[kk][r] = W[((size_t)d * GATES + g0 + r) * K + k0 + kk];
    }
    __syncthreads();
#pragma unroll
    for (int kk = 0; kk < BK; ++kk) {
      const float4 wv  = *(const float4*)&Ws[kk][tx * 4];
      const float4 hv0 = *(const float4*)&Hs[kk][ty * 8];
      const float4 hv1 = *(const float4*)&Hs[kk][ty * 8 + 4];
      const float hr[8] = {hv0.x, hv0.y, hv0.z, hv0.w, hv1.x, hv1.y, hv1.z, hv1.w};
#pragma unroll
      for (int r = 0; r < 8; ++r) {
        acc[r][0] = fmaf(hr[r], wv.x, acc[r][0]);
        acc[r][1] = fmaf(hr[r], wv.y, acc[r][1]);
        acc[r][2] = fmaf(hr[r], wv.z, acc[r][2]);
        acc[r][3] = fmaf(hr[r], wv.w, acc[r][3]);
      }
    }
    __syncthreads();
  }

  const int gcol = g0 + tx * 4;
  const float4 bi = *(const float4*)&bih[d * GATES + gcol];
  const float4 bh = *(const float4*)&bhh[d * GATES + gcol];
  const float bx = bi.x + bh.x, by = bi.y + bh.y, bz = bi.z + bh.z, bw = bi.w + bh.w;
#pragma unroll
  for (int r = 0; r < 8; ++r) {
    size_t m = (size_t)(m0 + ty * 8 + r);
    float4 o = {acc[r][0] + bx, acc[r][1] + by, acc[r][2] + bz, acc[r][3] + bw};
    *(float4*)&pre[((size_t)d * MTOT + m) * GATES + gcol] = o;
  }
}

// ---------- kernel 4: recurrent LSTM, 4 waves/(b,d), LDS h broadcast, resident weights ----------
// EXACTLY round-4's structure (best so far, 1151 us) + the two residency
// ingredients proven in round 8: amdgpu_waves_per_eu(1,1) (relaxes the
// allocator's occupancy-driven VGPR budget to the 1 wave/EU we actually run)
// and a per-element "+v" pin. Round 4 ran at VGPR_Count=52 -> its 64
// weights/lane were demoted and reloaded every step (vmcnt stall mid-matvec).
// Thread g owns gate row g. Wave w = gate type; each wave keeps a PRIVATE h
// replica in h_s[w] (written per-lane, read wave-uniform broadcast). Cross-wave
// exchange: ACTIVATED gate values through parity-double-buffered abuf. Sync =
// raw asm "s_waitcnt lgkmcnt(0); s_barrier": no vmcnt drain -> 4-deep HBM
// prefetch of pre stays in flight across steps.
// Race-freedom (1 barrier/step): a wave's lgkmcnt(0) before barrier t+1 proves
// its parity-p reads of step t completed; the next parity-p write happens only
// after barrier t+1.
__global__ __attribute__((amdgpu_waves_per_eu(1, 1)))
__launch_bounds__(256) void k_lstm4w(const float* __restrict__ pre, // [2][B*T][256]
                                     const float* __restrict__ whh, // [2][256][64]
                                     float* __restrict__ hout,      // [B][T][128]
                                     float* __restrict__ out,       // [B][128]
                                     int final_layer) {
  const int b = blockIdx.x, d = blockIdx.y;
  const int g = threadIdx.x;
  const int w = g >> 6;            // wave id == gate type (0:i 1:f 2:g 3:o)
  const int j = g & 63;            // hidden unit
  __shared__ __align__(16) float h_s[4][HID];
  __shared__ float abuf[2][GATES];          // activated gate values

  float wv[64];                    // 64 VGPRs of weights: row g of whh[d]
  const float4* wr = (const float4*)(whh + ((size_t)d * GATES + g) * HID);
#pragma unroll
  for (int kk = 0; kk < 16; ++kk) {
    const float4 t4 = wr[kk];
    wv[4 * kk + 0] = t4.x; wv[4 * kk + 1] = t4.y;
    wv[4 * kk + 2] = t4.z; wv[4 * kk + 3] = t4.w;
  }
#pragma unroll
  for (int kk = 0; kk < 64; ++kk) {
    asm volatile("" : "+v"(wv[kk]));  // pin: with waves_per_eu(1,1) these stay VGPR-resident
  }

  h_s[w][j] = 0.f;
  float c = 0.f, sum = 0.f;
  __syncthreads();                 // one-time (weight loads drained here, fine)

  const size_t base = ((size_t)d * BB + b) * (size_t)TT;
  const int t0 = d ? (TT - 1) : 0;
  const int dt = d ? -1 : 1;
  const float* pp = pre + (base + (size_t)t0) * GATES + g;
  const ptrdiff_t pstr = (ptrdiff_t)dt * GATES;

  float pf0 = pp[0], pf1 = pp[pstr], pf2 = pp[pstr * 2], pf3 = pp[pstr * 3];

#define LSTM_STEP(TK, PAR, PF)                                                 \
  do {                                                                         \
    float a0 = 0.f, a1 = 0.f, a2 = 0.f, a3 = 0.f;                              \
    const float4* h4 = (const float4*)&h_s[w][0];                              \
    _Pragma("unroll")                                                          \
    for (int kk = 0; kk < 16; ++kk) {                                          \
      const float4 hv = h4[kk];   /* wave-uniform addr: broadcast, no conflict */ \
      a0 = fmaf(hv.x, wv[4 * kk + 0], a0);                                     \
      a1 = fmaf(hv.y, wv[4 * kk + 1], a1);                                     \
      a2 = fmaf(hv.z, wv[4 * kk + 2], a2);                                     \
      a3 = fmaf(hv.w, wv[4 * kk + 3], a3);                                     \
    }                                                                          \
    const float z = ((a0 + a1) + (a2 + a3)) + (PF);                            \
    const float act = (w == 2) ? tanh_(z) : sigm(z);  /* wave-uniform branch */ \
    abuf[PAR][g] = act;                                                        \
    asm volatile("s_waitcnt lgkmcnt(0)\n\ts_barrier" ::: "memory");            \
    const float ig = abuf[PAR][j],           fg = abuf[PAR][HID + j];          \
    const float gg = abuf[PAR][2 * HID + j], og = abuf[PAR][3 * HID + j];      \
    c = fmaf(fg, c, ig * gg);                                                  \
    const float hv2 = og * tanh_(c);                                           \
    h_s[w][j] = hv2;                                                           \
    if (final_layer) sum += hv2;                                               \
    else if (w == 0)                                                           \
      hout[((size_t)b * TT + (size_t)(t0 + dt * (TK))) * (2 * HID) + d * HID + j] = hv2; \
  } while (0)

  for (int t = 0; t < TT; t += 4) {
    LSTM_STEP(t + 0, 0, pf0);
    { int ip = t + 4; if (ip >= TT) ip = 0; pf0 = pp[pstr * (ptrdiff_t)ip]; }
    LSTM_STEP(t + 1, 1, pf1);
    { int ip = t + 5; if (ip >= TT) ip = 0; pf1 = pp[pstr * (ptrdiff_t)ip]; }
    LSTM_STEP(t + 2, 0, pf2);
    { int ip = t + 6; if (ip >= TT) ip = 0; pf2 = pp[pstr * (ptrdiff_t)ip]; }
    LSTM_STEP(t + 3, 1, pf3);
    { int ip = t + 7; if (ip >= TT) ip = 0; pf3 = pp[pstr * (ptrdiff_t)ip]; }
  }
#undef LSTM_STEP

  if (final_layer && w == 0) out[b * (2 * HID) + d * HID + j] = sum * (1.0f / (float)TT);
}

// ---------- launch ----------
extern "C" void kernel_launch(void* const* d_in, const int* in_sizes, int n_in,
                              void* d_out, int out_size, void* d_ws, size_t ws_size,
                              hipStream_t stream) {
  const float* x         = (const float*)d_in[0];
  const float* binpoints = (const float*)d_in[1];
  const float* w_ih[3] = {(const float*)d_in[2], (const float*)d_in[6],  (const float*)d_in[10]};
  const float* w_hh[3] = {(const float*)d_in[3], (const float*)d_in[7],  (const float*)d_in[11]};
  const float* b_ih[3] = {(const float*)d_in[4], (const float*)d_in[8],  (const float*)d_in[12]};
  const float* b_hh[3] = {(const float*)d_in[5], (const float*)d_in[9],  (const float*)d_in[13]};
  float* out = (float*)d_out;

  // workspace layout (~349 MB):
  //   pre  : 2*MTOT*256 f32 = 262,144,000 B
  //   Hbuf : MTOT*128 f32   =  65,536,000 B
  //   h0   : MTOT*40 f32    =  20,480,000 B
  //   fbank: 40*257 f32, lohi: 80 i32
  float* pre   = (float*)d_ws;
  float* Hbuf  = pre  + (size_t)2 * MTOT * GATES;
  float* h0    = Hbuf + (size_t)MTOT * 128;
  float* fbank = h0   + (size_t)MTOT * NFILT;
  int*   lohi  = (int*)(fbank + NFILT * NBINS);

  k_fbank<<<1, 256, 0, stream>>>(binpoints, fbank, lohi);
  k_feat<<<MTOT, 64, 0, stream>>>(x, fbank, lohi, h0);

  // layer 0 (K=40)
  k_gemm<40, 40><<<dim3(MTOT / 128, GATES / 64, 2), 256, 0, stream>>>(h0, w_ih[0], b_ih[0], b_hh[0], pre);
  k_lstm4w<<<dim3(BB, 2), 256, 0, stream>>>(pre, w_hh[0], Hbuf, out, 0);

  // layer 1 (K=128)
  k_gemm<128, 32><<<dim3(MTOT / 128, GATES / 64, 2), 256, 0, stream>>>(Hbuf, w_ih[1], b_ih[1], b_hh[1], pre);
  k_lstm4w<<<dim3(BB, 2), 256, 0, stream>>>(pre, w_hh[1], Hbuf, out, 0);

  // layer 2 (K=128)
  k_gemm<128, 32><<<dim3(MTOT / 128, GATES / 64, 2), 256, 0, stream>>>(Hbuf, w_ih[2], b_ih[2], b_hh[2], pre);
  k_lstm4w<<<dim3(BB, 2), 256, 0, stream>>>(pre, w_hh[2], Hbuf, out, 1);
}

// Round 11
// 3376.161 us; speedup vs baseline: 2.1731x; 1.1976x over previous
//
#include <hip/hip_runtime.h>
#include <cstdint>
#include <cstddef>

#define NFILT 40
#define NBINS 257
#define HID   64
#define BB    64      // batch
#define TT    2000    // time
#define GATES 256     // 4*HID
#define MTOT  (BB*TT) // 128000 rows

// ---------- activations ----------
__device__ __forceinline__ float sigm(float x) {
  return 1.0f / (1.0f + __expf(-x));
}
__device__ __forceinline__ float tanh_(float x) {
  float e = __expf(-2.0f * fabsf(x));
  float r = (1.0f - e) / (1.0f + e);
  return copysignf(r, x);
}

// quad butterfly via DPP (VALU pipe, no LDS): after bfly2(bfly1(x)) every lane
// of each 4-lane quad holds the quad sum. (numerically verified in round 5)
__device__ __forceinline__ float bfly1(float x) {
  int i = __builtin_amdgcn_mov_dpp(__float_as_int(x), 0xB1, 0xF, 0xF, true); // quad_perm [1,0,3,2]
  return x + __int_as_float(i);
}
__device__ __forceinline__ float bfly2(float x) {
  int i = __builtin_amdgcn_mov_dpp(__float_as_int(x), 0x4E, 0xF, 0xF, true); // quad_perm [2,3,0,1]
  return x + __int_as_float(i);
}

__device__ __forceinline__ float dot16(const float4* w, float4 a, float4 b,
                                       float4 c2, float4 d2, float acc) {
  acc = fmaf(a.x, w[0].x, acc);  acc = fmaf(a.y, w[0].y, acc);
  acc = fmaf(a.z, w[0].z, acc);  acc = fmaf(a.w, w[0].w, acc);
  acc = fmaf(b.x, w[1].x, acc);  acc = fmaf(b.y, w[1].y, acc);
  acc = fmaf(b.z, w[1].z, acc);  acc = fmaf(b.w, w[1].w, acc);
  acc = fmaf(c2.x, w[2].x, acc); acc = fmaf(c2.y, w[2].y, acc);
  acc = fmaf(c2.z, w[2].z, acc); acc = fmaf(c2.w, w[2].w, acc);
  acc = fmaf(d2.x, w[3].x, acc); acc = fmaf(d2.y, w[3].y, acc);
  acc = fmaf(d2.z, w[3].z, acc); acc = fmaf(d2.w, w[3].w, acc);
  return acc;
}

// ---------- kernel 1: build fbank (40x257) + per-filter support bounds ----------
__global__ void k_fbank(const float* __restrict__ binpoints,
                        float* __restrict__ fbank,
                        int* __restrict__ lohi /*[2*NFILT]*/) {
  __shared__ float b[NFILT + 2];
  int tid = threadIdx.x;
  if (tid < NFILT + 2) b[tid] = binpoints[tid];
  __syncthreads();
  if (tid < NFILT) {
    if (tid == NFILT - 1) { lohi[tid] = 0; lohi[NFILT + tid] = 0; }
    else {
      int lo = (int)floorf(b[tid]);
      int hi = (int)floorf(b[tid + 2]);
      if (lo < 0) lo = 0;
      if (hi > NBINS) hi = NBINS;
      lohi[tid] = lo; lohi[NFILT + tid] = hi;
    }
  }
  for (int idx = tid; idx < NFILT * NBINS; idx += blockDim.x) {
    int f = idx / NBINS, i = idx - f * NBINS;
    float bj = b[f], bj1 = b[f + 1], bj2 = b[f + 2];
    float fb0 = floorf(bj), fb1 = floorf(bj1), fb2 = floorf(bj2);
    float fi = (float)i;
    bool rise = (fi >= fb0) && (fi < fb1);
    bool fall = (fi >= fb1) && (fi < fb2);
    float d1 = bj1 - bj;  d1 = (d1 > 0.f) ? d1 : 1.f;
    float d2 = bj2 - bj1; d2 = (d2 > 0.f) ? d2 : 1.f;
    float rv = (fi - bj)  / (d1 * d1);
    float fv = (bj2 - fi) / (d2 * d2);
    float v = fall ? fv : (rise ? rv : 0.f);
    if (f == NFILT - 1) v = 0.f;
    fbank[idx] = v;
  }
}

// ---------- kernel 2: featurize  h0[bt][f] = log(filt + 1e-10) ----------
__global__ __launch_bounds__(64) void k_feat(const float* __restrict__ x,
                                             const float* __restrict__ fbank,
                                             const int* __restrict__ lohi,
                                             float* __restrict__ h0) {
  int bt = blockIdx.x;
  __shared__ float xs[NBINS];
  const float* xr = x + (size_t)bt * NBINS;
  for (int i = threadIdx.x; i < NBINS; i += 64) xs[i] = xr[i];
  __syncthreads();
  int f = threadIdx.x;
  if (f < NFILT) {
    float acc = 0.f;
    int lo = lohi[f], hi = lohi[NFILT + f];
    for (int i = lo; i < hi; ++i) acc = fmaf(xs[i], fbank[f * NBINS + i], acc);
    float val = (f == 0) ? xs[0] : acc;
    h0[(size_t)bt * NFILT + f] = logf(val + 1e-10f);
  }
}

// ---------- kernel 3: fp32 GEMM  pre[d][m][g] = H[m][:]·W[d][g][:] + bih + bhh ----------
template <int K, int BK>
__global__ __launch_bounds__(256) void k_gemm(const float* __restrict__ Hm,   // [MTOT][K]
                                              const float* __restrict__ W,    // [2][256][K]
                                              const float* __restrict__ bih,  // [2][256]
                                              const float* __restrict__ bhh,  // [2][256]
                                              float* __restrict__ pre) {      // [2][MTOT][256]
  constexpr int BM = 128, BN = 64;
  __shared__ float Hs[BK][BM + 4];
  __shared__ float Ws[BK][BN + 4];
  const int d  = blockIdx.z;
  const int m0 = blockIdx.x * BM;
  const int g0 = blockIdx.y * BN;
  const int tid = threadIdx.x;
  const int tx = tid & 15, ty = tid >> 4;

  float acc[8][4];
#pragma unroll
  for (int r = 0; r < 8; ++r)
#pragma unroll
    for (int j = 0; j < 4; ++j) acc[r][j] = 0.f;

  for (int k0 = 0; k0 < K; k0 += BK) {
    constexpr int HL = BM * BK / 256;
#pragma unroll
    for (int i = 0; i < HL; ++i) {
      int flat = tid + i * 256;
      int r = flat / BK, kk = flat - r * BK;
      Hs[kk][r] = Hm[(size_t)(m0 + r) * K + k0 + kk];
    }
    constexpr int WL = BN * BK / 256;
#pragma unroll
    for (int i = 0; i < WL; ++i) {
      int flat = tid + i * 256;
      int r = flat / BK, kk = flat - r * BK;
      Ws[kk][r] = W[((size_t)d * GATES + g0 + r) * K + k0 + kk];
    }
    __syncthreads();
#pragma unroll
    for (int kk = 0; kk < BK; ++kk) {
      const float4 wv  = *(const float4*)&Ws[kk][tx * 4];
      const float4 hv0 = *(const float4*)&Hs[kk][ty * 8];
      const float4 hv1 = *(const float4*)&Hs[kk][ty * 8 + 4];
      const float hr[8] = {hv0.x, hv0.y, hv0.z, hv0.w, hv1.x, hv1.y, hv1.z, hv1.w};
#pragma unroll
      for (int r = 0; r < 8; ++r) {
        acc[r][0] = fmaf(hr[r], wv.x, acc[r][0]);
        acc[r][1] = fmaf(hr[r], wv.y, acc[r][1]);
        acc[r][2] = fmaf(hr[r], wv.z, acc[r][2]);
        acc[r][3] = fmaf(hr[r], wv.w, acc[r][3]);
      }
    }
    __syncthreads();
  }

  const int gcol = g0 + tx * 4;
  const float4 bi = *(const float4*)&bih[d * GATES + gcol];
  const float4 bh = *(const float4*)&bhh[d * GATES + gcol];
  const float bx = bi.x + bh.x, by = bi.y + bh.y, bz = bi.z + bh.z, bw = bi.w + bh.w;
#pragma unroll
  for (int r = 0; r < 8; ++r) {
    size_t m = (size_t)(m0 + ty * 8 + r);
    float4 o = {acc[r][0] + bx, acc[r][1] + by, acc[r][2] + bz, acc[r][3] + bw};
    *(float4*)&pre[((size_t)d * MTOT + m) * GATES + gcol] = o;
  }
}

// ---------- kernel 4: recurrent LSTM, quad-per-unit, ONE chain per 256-thread block ----------
// Round-5's numerically-verified quad layout with its two perf bugs fixed:
// one chain/block (4 waves, 1 wave/SIMD -> full issue rate, vs R5's 2/SIMD) and
// resident weights (waves_per_eu(1,1) + pin, proven in R8/R10).
// Wave w owns units 16w..16w+15; lane (u,p): u = 16w + (l>>2), p = l&3 holds a
// 16-wide k-slice of ALL 4 gate rows of unit u (64 floats, VGPR-resident).
// Per step: 4 broadcast ds_read_b128 (h-slice) -> 64 fmac partial dots (+own
// pre via gate mask) -> quad DPP butterfly completes all 4 z in-register
// (replaces the abuf LDS-exchange round trip of R4/R10 entirely) -> redundant
// per-quad activations (4 independent TRANS, parallel latency) + c/h update ->
// p==0 lanes write h to parity-double-buffered hs[2][64] -> raw asm
// "lgkmcnt(0); s_barrier" (no vmcnt drain: 4-deep HBM prefetch stays in
// flight). ONE LDS round-trip + ONE barrier per step on the serial path.
// Race-freedom: step t reads hs[t&1], writes hs[(t+1)&1]; lgkmcnt(0) before
// barrier proves reads+writes done; a wave cannot write parity p again without
// passing two barriers.
__global__ __attribute__((amdgpu_waves_per_eu(1, 1)))
__launch_bounds__(256) void k_lstmq(const float* __restrict__ pre, // [2][B*T][256]
                                    const float* __restrict__ whh, // [2][256][64]
                                    float* __restrict__ hout,      // [B][T][128]
                                    float* __restrict__ out,       // [B][128]
                                    int final_layer) {
  const int b   = blockIdx.x;
  const int d   = blockIdx.y;
  const int tid = threadIdx.x;
  const int wl  = tid >> 6;          // wave 0..3
  const int l   = tid & 63;
  const int u   = wl * 16 + (l >> 2); // hidden unit owned by this quad
  const int p   = l & 3;              // k-slice / gate-part
  const int p16 = p * 16;

  __shared__ __align__(16) float hs[2][HID];   // parity double-buffered h

  // weights: wq[q][c] = W[d][q*64+u][16p + 4c .. +3]  (64 floats/lane)
  float4 wq[4][4];
#pragma unroll
  for (int q = 0; q < 4; ++q) {
    const float4* wr = (const float4*)(whh + ((size_t)d * GATES + q * HID + u) * HID + p16);
#pragma unroll
    for (int c2 = 0; c2 < 4; ++c2) wq[q][c2] = wr[c2];
  }
  {
    float* wf = (float*)&wq[0][0];
#pragma unroll
    for (int i = 0; i < 64; ++i) asm volatile("" : "+v"(wf[i]));  // pin resident
  }
  // gate masks: lane adds its own prefetched pre value to exactly one gate partial
  const float m0 = (p == 0) ? 1.f : 0.f;
  const float m1 = (p == 1) ? 1.f : 0.f;
  const float m2 = (p == 2) ? 1.f : 0.f;
  const float m3 = (p == 3) ? 1.f : 0.f;

  if (tid < HID) { hs[0][tid] = 0.f; hs[1][tid] = 0.f; }
  float c = 0.f, sum = 0.f;
  __syncthreads();   // one-time full barrier

  const int t0 = d ? (TT - 1) : 0;
  const int dt = d ? -1 : 1;
  const float* pp = pre + ((size_t)d * MTOT + (size_t)b * TT + t0) * GATES + (p * HID + u);
  const ptrdiff_t pstr = (ptrdiff_t)dt * GATES;

  float pf0 = pp[0], pf1 = pp[pstr], pf2 = pp[pstr * 2], pf3 = pp[pstr * 3];

#define LSTM_STEP(TK, PAR, PF)                                                  \
  do {                                                                          \
    const float4* h4 = (const float4*)&hs[PAR][p16];                            \
    const float4 hA = h4[0], hB = h4[1], hC = h4[2], hD = h4[3];                \
    float a0 = dot16(wq[0], hA, hB, hC, hD, (PF) * m0);                         \
    float a1 = dot16(wq[1], hA, hB, hC, hD, (PF) * m1);                         \
    float a2 = dot16(wq[2], hA, hB, hC, hD, (PF) * m2);                         \
    float a3 = dot16(wq[3], hA, hB, hC, hD, (PF) * m3);                         \
    a0 = bfly2(bfly1(a0)); a1 = bfly2(bfly1(a1));                               \
    a2 = bfly2(bfly1(a2)); a3 = bfly2(bfly1(a3));                               \
    const float ig = sigm(a0), fg = sigm(a1), gg = tanh_(a2), og = sigm(a3);    \
    c = fmaf(fg, c, ig * gg);                                                   \
    const float hvv = og * tanh_(c);                                            \
    if (p == 0) hs[(PAR) ^ 1][u] = hvv;                                         \
    asm volatile("s_waitcnt lgkmcnt(0)\n\ts_barrier" ::: "memory");             \
    if (final_layer) sum += hvv;                                                \
    else if (p == 0)                                                            \
      hout[((size_t)b * TT + (size_t)(t0 + dt * (TK))) * (2 * HID) + d * HID + u] = hvv; \
  } while (0)

  for (int t = 0; t < TT; t += 4) {
    LSTM_STEP(t + 0, 0, pf0);
    { int ip = t + 4; if (ip >= TT) ip = 0; pf0 = pp[pstr * (ptrdiff_t)ip]; }
    LSTM_STEP(t + 1, 1, pf1);
    { int ip = t + 5; if (ip >= TT) ip = 0; pf1 = pp[pstr * (ptrdiff_t)ip]; }
    LSTM_STEP(t + 2, 0, pf2);
    { int ip = t + 6; if (ip >= TT) ip = 0; pf2 = pp[pstr * (ptrdiff_t)ip]; }
    LSTM_STEP(t + 3, 1, pf3);
    { int ip = t + 7; if (ip >= TT) ip = 0; pf3 = pp[pstr * (ptrdiff_t)ip]; }
  }
#undef LSTM_STEP

  if (final_layer && p == 0) out[b * (2 * HID) + d * HID + u] = sum * (1.0f / (float)TT);
}

// ---------- launch ----------
extern "C" void kernel_launch(void* const* d_in, const int* in_sizes, int n_in,
                              void* d_out, int out_size, void* d_ws, size_t ws_size,
                              hipStream_t stream) {
  const float* x         = (const float*)d_in[0];
  const float* binpoints = (const float*)d_in[1];
  const float* w_ih[3] = {(const float*)d_in[2], (const float*)d_in[6],  (const float*)d_in[10]};
  const float* w_hh[3] = {(const float*)d_in[3], (const float*)d_in[7],  (const float*)d_in[11]};
  const float* b_ih[3] = {(const float*)d_in[4], (const float*)d_in[8],  (const float*)d_in[12]};
  const float* b_hh[3] = {(const float*)d_in[5], (const float*)d_in[9],  (const float*)d_in[13]};
  float* out = (float*)d_out;

  // workspace layout (~349 MB):
  //   pre  : 2*MTOT*256 f32 = 262,144,000 B
  //   Hbuf : MTOT*128 f32   =  65,536,000 B
  //   h0   : MTOT*40 f32    =  20,480,000 B
  //   fbank: 40*257 f32, lohi: 80 i32
  float* pre   = (float*)d_ws;
  float* Hbuf  = pre  + (size_t)2 * MTOT * GATES;
  float* h0    = Hbuf + (size_t)MTOT * 128;
  float* fbank = h0   + (size_t)MTOT * NFILT;
  int*   lohi  = (int*)(fbank + NFILT * NBINS);

  k_fbank<<<1, 256, 0, stream>>>(binpoints, fbank, lohi);
  k_feat<<<MTOT, 64, 0, stream>>>(x, fbank, lohi, h0);

  // layer 0 (K=40)
  k_gemm<40, 40><<<dim3(MTOT / 128, GATES / 64, 2), 256, 0, stream>>>(h0, w_ih[0], b_ih[0], b_hh[0], pre);
  k_lstmq<<<dim3(BB, 2), 256, 0, stream>>>(pre, w_hh[0], Hbuf, out, 0);

  // layer 1 (K=128)
  k_gemm<128, 32><<<dim3(MTOT / 128, GATES / 64, 2), 256, 0, stream>>>(Hbuf, w_ih[1], b_ih[1], b_hh[1], pre);
  k_lstmq<<<dim3(BB, 2), 256, 0, stream>>>(pre, w_hh[1], Hbuf, out, 0);

  // layer 2 (K=128)
  k_gemm<128, 32><<<dim3(MTOT / 128, GATES / 64, 2), 256, 0, stream>>>(Hbuf, w_ih[2], b_ih[2], b_hh[2], pre);
  k_lstmq<<<dim3(BB, 2), 256, 0, stream>>>(pre, w_hh[2], Hbuf, out, 1);
}

// Round 12
// 3139.661 us; speedup vs baseline: 2.3368x; 1.0753x over previous
//
#include <hip/hip_runtime.h>
#include <cstdint>
#include <cstddef>

#define NFILT 40
#define NBINS 257
#define HID   64
#define BB    64      // batch
#define TT    2000    // time
#define GATES 256     // 4*HID
#define MTOT  (BB*TT) // 128000 rows

// ---------- activations ----------
__device__ __forceinline__ float sigm(float x) {
  return 1.0f / (1.0f + __expf(-x));
}

// quad butterfly via DPP (VALU pipe, no LDS): after bfly2(bfly1(x)) every lane
// of each 4-lane quad holds the quad sum. (numerically verified in round 5/11)
__device__ __forceinline__ float bfly1(float x) {
  int i = __builtin_amdgcn_mov_dpp(__float_as_int(x), 0xB1, 0xF, 0xF, true); // quad_perm [1,0,3,2]
  return x + __int_as_float(i);
}
__device__ __forceinline__ float bfly2(float x) {
  int i = __builtin_amdgcn_mov_dpp(__float_as_int(x), 0x4E, 0xF, 0xF, true); // quad_perm [2,3,0,1]
  return x + __int_as_float(i);
}
// quad broadcast: every lane gets lane q's value (quad_perm [q,q,q,q])
#define QB(x, ctrl) __int_as_float(__builtin_amdgcn_mov_dpp(__float_as_int(x), (ctrl), 0xF, 0xF, true))

__device__ __forceinline__ float dot16(const float4* w, float4 a, float4 b,
                                       float4 c2, float4 d2, float acc) {
  acc = fmaf(a.x, w[0].x, acc);  acc = fmaf(a.y, w[0].y, acc);
  acc = fmaf(a.z, w[0].z, acc);  acc = fmaf(a.w, w[0].w, acc);
  acc = fmaf(b.x, w[1].x, acc);  acc = fmaf(b.y, w[1].y, acc);
  acc = fmaf(b.z, w[1].z, acc);  acc = fmaf(b.w, w[1].w, acc);
  acc = fmaf(c2.x, w[2].x, acc); acc = fmaf(c2.y, w[2].y, acc);
  acc = fmaf(c2.z, w[2].z, acc); acc = fmaf(c2.w, w[2].w, acc);
  acc = fmaf(d2.x, w[3].x, acc); acc = fmaf(d2.y, w[3].y, acc);
  acc = fmaf(d2.z, w[3].z, acc); acc = fmaf(d2.w, w[3].w, acc);
  return acc;
}

// ---------- kernel 1: build fbank (40x257) + per-filter support bounds ----------
__global__ void k_fbank(const float* __restrict__ binpoints,
                        float* __restrict__ fbank,
                        int* __restrict__ lohi /*[2*NFILT]*/) {
  __shared__ float b[NFILT + 2];
  int tid = threadIdx.x;
  if (tid < NFILT + 2) b[tid] = binpoints[tid];
  __syncthreads();
  if (tid < NFILT) {
    if (tid == NFILT - 1) { lohi[tid] = 0; lohi[NFILT + tid] = 0; }
    else {
      int lo = (int)floorf(b[tid]);
      int hi = (int)floorf(b[tid + 2]);
      if (lo < 0) lo = 0;
      if (hi > NBINS) hi = NBINS;
      lohi[tid] = lo; lohi[NFILT + tid] = hi;
    }
  }
  for (int idx = tid; idx < NFILT * NBINS; idx += blockDim.x) {
    int f = idx / NBINS, i = idx - f * NBINS;
    float bj = b[f], bj1 = b[f + 1], bj2 = b[f + 2];
    float fb0 = floorf(bj), fb1 = floorf(bj1), fb2 = floorf(bj2);
    float fi = (float)i;
    bool rise = (fi >= fb0) && (fi < fb1);
    bool fall = (fi >= fb1) && (fi < fb2);
    float d1 = bj1 - bj;  d1 = (d1 > 0.f) ? d1 : 1.f;
    float d2 = bj2 - bj1; d2 = (d2 > 0.f) ? d2 : 1.f;
    float rv = (fi - bj)  / (d1 * d1);
    float fv = (bj2 - fi) / (d2 * d2);
    float v = fall ? fv : (rise ? rv : 0.f);
    if (f == NFILT - 1) v = 0.f;
    fbank[idx] = v;
  }
}

// ---------- kernel 2: featurize  h0[bt][f] = log(filt + 1e-10) ----------
__global__ __launch_bounds__(64) void k_feat(const float* __restrict__ x,
                                             const float* __restrict__ fbank,
                                             const int* __restrict__ lohi,
                                             float* __restrict__ h0) {
  int bt = blockIdx.x;
  __shared__ float xs[NBINS];
  const float* xr = x + (size_t)bt * NBINS;
  for (int i = threadIdx.x; i < NBINS; i += 64) xs[i] = xr[i];
  __syncthreads();
  int f = threadIdx.x;
  if (f < NFILT) {
    float acc = 0.f;
    int lo = lohi[f], hi = lohi[NFILT + f];
    for (int i = lo; i < hi; ++i) acc = fmaf(xs[i], fbank[f * NBINS + i], acc);
    float val = (f == 0) ? xs[0] : acc;
    h0[(size_t)bt * NFILT + f] = logf(val + 1e-10f);
  }
}

// ---------- kernel 3: fp32 GEMM, 128x128 tile, 8x8 micro (64 fmac per 4 LDS b128) ----------
template <int K, int BK>
__global__ __launch_bounds__(256) void k_gemm(const float* __restrict__ Hm,   // [MTOT][K]
                                              const float* __restrict__ W,    // [2][256][K]
                                              const float* __restrict__ bih,  // [2][256]
                                              const float* __restrict__ bhh,  // [2][256]
                                              float* __restrict__ pre) {      // [2][MTOT][256]
  constexpr int BM = 128, BN = 128;
  __shared__ float Hs[BK][BM + 4];
  __shared__ float Ws[BK][BN + 4];
  const int d  = blockIdx.z;
  const int m0 = blockIdx.x * BM;
  const int g0 = blockIdx.y * BN;
  const int tid = threadIdx.x;
  const int tx = tid & 15, ty = tid >> 4;   // 16x16 thread grid, 8x8 micro-tile

  float acc[8][8];
#pragma unroll
  for (int r = 0; r < 8; ++r)
#pragma unroll
    for (int j = 0; j < 8; ++j) acc[r][j] = 0.f;

  for (int k0 = 0; k0 < K; k0 += BK) {
    constexpr int HL = BM * BK / 256;
#pragma unroll
    for (int i = 0; i < HL; ++i) {
      int flat = tid + i * 256;
      int r = flat / BK, kk = flat - r * BK;
      Hs[kk][r] = Hm[(size_t)(m0 + r) * K + k0 + kk];
    }
    constexpr int WL = BN * BK / 256;
#pragma unroll
    for (int i = 0; i < WL; ++i) {
      int flat = tid + i * 256;
      int r = flat / BK, kk = flat - r * BK;
      Ws[kk][r] = W[((size_t)d * GATES + g0 + r) * K + k0 + kk];
    }
    __syncthreads();
#pragma unroll
    for (int kk = 0; kk < BK; ++kk) {
      const float4 wv0 = *(const float4*)&Ws[kk][tx * 8];
      const float4 wv1 = *(const float4*)&Ws[kk][tx * 8 + 4];
      const float4 hv0 = *(const float4*)&Hs[kk][ty * 8];
      const float4 hv1 = *(const float4*)&Hs[kk][ty * 8 + 4];
      const float hr[8] = {hv0.x, hv0.y, hv0.z, hv0.w, hv1.x, hv1.y, hv1.z, hv1.w};
      const float wc[8] = {wv0.x, wv0.y, wv0.z, wv0.w, wv1.x, wv1.y, wv1.z, wv1.w};
#pragma unroll
      for (int r = 0; r < 8; ++r)
#pragma unroll
        for (int j = 0; j < 8; ++j)
          acc[r][j] = fmaf(hr[r], wc[j], acc[r][j]);
    }
    __syncthreads();
  }

  const int gcol = g0 + tx * 8;
  float bsum[8];
#pragma unroll
  for (int i = 0; i < 8; ++i)
    bsum[i] = bih[d * GATES + gcol + i] + bhh[d * GATES + gcol + i];
#pragma unroll
  for (int r = 0; r < 8; ++r) {
    size_t m = (size_t)(m0 + ty * 8 + r);
    float4 o0 = {acc[r][0] + bsum[0], acc[r][1] + bsum[1], acc[r][2] + bsum[2], acc[r][3] + bsum[3]};
    float4 o1 = {acc[r][4] + bsum[4], acc[r][5] + bsum[5], acc[r][6] + bsum[6], acc[r][7] + bsum[7]};
    *(float4*)&pre[((size_t)d * MTOT + m) * GATES + gcol] = o0;
    *(float4*)&pre[((size_t)d * MTOT + m) * GATES + gcol + 4] = o1;
  }
}

// ---------- kernel 4: recurrent LSTM, quad-per-unit, single-act + DPP quad-broadcast ----------
// Round-11 structure (925 us) with issue-count cuts:
//  * ONE activation per lane: lane p activates only its own gate's z. sigma/tanh
//    unified via tanh(x) = 2*sigm(2x)-1 with per-lane hoisted constants
//    (sA: input scale, aA/aB: output fixup) -> no divergence, one TRANS chain.
//  * 4 DPP quad_perm broadcasts (0x00/0x55/0xAA/0xFF) deliver ig/fg/gg/og to all
//    quad lanes in-register (replaces 4 redundant act chains per lane).
//  * pre (pf) added once to the selected z AFTER the butterfly (drops 4 mask muls).
//  * tanh(c) also sigma-unified (9 -> 6 ops).
// Everything else identical: resident weights (waves_per_eu(1,1) + pin), parity
// double-buffered hs, raw asm "lgkmcnt(0); s_barrier" (no vmcnt drain -> 4-deep
// HBM prefetch stays in flight), ONE LDS round-trip + ONE barrier per step.
__global__ __attribute__((amdgpu_waves_per_eu(1, 1)))
__launch_bounds__(256) void k_lstmq(const float* __restrict__ pre, // [2][B*T][256]
                                    const float* __restrict__ whh, // [2][256][64]
                                    float* __restrict__ hout,      // [B][T][128]
                                    float* __restrict__ out,       // [B][128]
                                    int final_layer) {
  const int b   = blockIdx.x;
  const int d   = blockIdx.y;
  const int tid = threadIdx.x;
  const int wl  = tid >> 6;          // wave 0..3
  const int l   = tid & 63;
  const int uu  = wl * 16 + (l >> 2); // hidden unit owned by this quad
  const int p   = l & 3;              // k-slice / gate index
  const int p16 = p * 16;

  __shared__ __align__(16) float hs[2][HID];   // parity double-buffered h

  // weights: wq[q][c] = W[d][q*64+uu][16p + 4c .. +3]  (64 floats/lane)
  float4 wq[4][4];
#pragma unroll
  for (int q = 0; q < 4; ++q) {
    const float4* wr = (const float4*)(whh + ((size_t)d * GATES + q * HID + uu) * HID + p16);
#pragma unroll
    for (int c2 = 0; c2 < 4; ++c2) wq[q][c2] = wr[c2];
  }
  {
    float* wf = (float*)&wq[0][0];
#pragma unroll
    for (int i = 0; i < 64; ++i) asm volatile("" : "+v"(wf[i]));  // pin resident
  }
  // per-lane activation constants: gate 2 (p==2) is tanh = 2*sigm(2x)-1
  const float sA = (p == 2) ? 2.f : 1.f;   // input scale
  const float aA = (p == 2) ? 2.f : 1.f;   // output scale
  const float aB = (p == 2) ? -1.f : 0.f;  // output bias
  const bool  p1 = (p & 1) != 0;
  const bool  p2 = (p & 2) != 0;

  if (tid < HID) { hs[0][tid] = 0.f; hs[1][tid] = 0.f; }
  float c = 0.f, sum = 0.f;
  __syncthreads();   // one-time full barrier

  const int t0 = d ? (TT - 1) : 0;
  const int dt = d ? -1 : 1;
  const float* pp = pre + ((size_t)d * MTOT + (size_t)b * TT + t0) * GATES + (p * HID + uu);
  const ptrdiff_t pstr = (ptrdiff_t)dt * GATES;

  float pf0 = pp[0], pf1 = pp[pstr], pf2 = pp[pstr * 2], pf3 = pp[pstr * 3];

#define LSTM_STEP(TK, PAR, PF)                                                  \
  do {                                                                          \
    const float4* h4 = (const float4*)&hs[PAR][p16];                            \
    const float4 hA = h4[0], hB = h4[1], hC = h4[2], hD = h4[3];                \
    float a0 = dot16(wq[0], hA, hB, hC, hD, 0.f);                               \
    float a1 = dot16(wq[1], hA, hB, hC, hD, 0.f);                               \
    float a2 = dot16(wq[2], hA, hB, hC, hD, 0.f);                               \
    float a3 = dot16(wq[3], hA, hB, hC, hD, 0.f);                               \
    a0 = bfly2(bfly1(a0)); a1 = bfly2(bfly1(a1));                               \
    a2 = bfly2(bfly1(a2)); a3 = bfly2(bfly1(a3));                               \
    const float t02 = p2 ? a2 : a0;                                             \
    const float t13 = p2 ? a3 : a1;                                             \
    const float zsel = (p1 ? t13 : t02) + (PF);                                 \
    const float act = fmaf(sigm(zsel * sA), aA, aB);                            \
    const float ig = QB(act, 0x00), fg = QB(act, 0x55);                         \
    const float gg = QB(act, 0xAA), og = QB(act, 0xFF);                         \
    c = fmaf(fg, c, ig * gg);                                                   \
    const float tc = fmaf(sigm(2.f * c), 2.f, -1.f);                            \
    const float hvv = og * tc;                                                  \
    if (p == 0) hs[(PAR) ^ 1][uu] = hvv;                                        \
    asm volatile("s_waitcnt lgkmcnt(0)\n\ts_barrier" ::: "memory");             \
    if (final_layer) sum += hvv;                                                \
    else if (p == 0)                                                            \
      hout[((size_t)b * TT + (size_t)(t0 + dt * (TK))) * (2 * HID) + d * HID + uu] = hvv; \
  } while (0)

  for (int t = 0; t < TT; t += 4) {
    LSTM_STEP(t + 0, 0, pf0);
    { int ip = t + 4; if (ip >= TT) ip = 0; pf0 = pp[pstr * (ptrdiff_t)ip]; }
    LSTM_STEP(t + 1, 1, pf1);
    { int ip = t + 5; if (ip >= TT) ip = 0; pf1 = pp[pstr * (ptrdiff_t)ip]; }
    LSTM_STEP(t + 2, 0, pf2);
    { int ip = t + 6; if (ip >= TT) ip = 0; pf2 = pp[pstr * (ptrdiff_t)ip]; }
    LSTM_STEP(t + 3, 1, pf3);
    { int ip = t + 7; if (ip >= TT) ip = 0; pf3 = pp[pstr * (ptrdiff_t)ip]; }
  }
#undef LSTM_STEP

  if (final_layer && p == 0) out[b * (2 * HID) + d * HID + uu] = sum * (1.0f / (float)TT);
}

// ---------- launch ----------
extern "C" void kernel_launch(void* const* d_in, const int* in_sizes, int n_in,
                              void* d_out, int out_size, void* d_ws, size_t ws_size,
                              hipStream_t stream) {
  const float* x         = (const float*)d_in[0];
  const float* binpoints = (const float*)d_in[1];
  const float* w_ih[3] = {(const float*)d_in[2], (const float*)d_in[6],  (const float*)d_in[10]};
  const float* w_hh[3] = {(const float*)d_in[3], (const float*)d_in[7],  (const float*)d_in[11]};
  const float* b_ih[3] = {(const float*)d_in[4], (const float*)d_in[8],  (const float*)d_in[12]};
  const float* b_hh[3] = {(const float*)d_in[5], (const float*)d_in[9],  (const float*)d_in[13]};
  float* out = (float*)d_out;

  // workspace layout (~349 MB):
  //   pre  : 2*MTOT*256 f32 = 262,144,000 B
  //   Hbuf : MTOT*128 f32   =  65,536,000 B
  //   h0   : MTOT*40 f32    =  20,480,000 B
  //   fbank: 40*257 f32, lohi: 80 i32
  float* pre   = (float*)d_ws;
  float* Hbuf  = pre  + (size_t)2 * MTOT * GATES;
  float* h0    = Hbuf + (size_t)MTOT * 128;
  float* fbank = h0   + (size_t)MTOT * NFILT;
  int*   lohi  = (int*)(fbank + NFILT * NBINS);

  k_fbank<<<1, 256, 0, stream>>>(binpoints, fbank, lohi);
  k_feat<<<MTOT, 64, 0, stream>>>(x, fbank, lohi, h0);

  // layer 0 (K=40)
  k_gemm<40, 40><<<dim3(MTOT / 128, GATES / 128, 2), 256, 0, stream>>>(h0, w_ih[0], b_ih[0], b_hh[0], pre);
  k_lstmq<<<dim3(BB, 2), 256, 0, stream>>>(pre, w_hh[0], Hbuf, out, 0);

  // layer 1 (K=128)
  k_gemm<128, 32><<<dim3(MTOT / 128, GATES / 128, 2), 256, 0, stream>>>(Hbuf, w_ih[1], b_ih[1], b_hh[1], pre);
  k_lstmq<<<dim3(BB, 2), 256, 0, stream>>>(pre, w_hh[1], Hbuf, out, 0);

  // layer 2 (K=128)
  k_gemm<128, 32><<<dim3(MTOT / 128, GATES / 128, 2), 256, 0, stream>>>(Hbuf, w_ih[2], b_ih[2], b_hh[2], pre);
  k_lstmq<<<dim3(BB, 2), 256, 0, stream>>>(pre, w_hh[2], Hbuf, out, 1);
}